// Round 2
// baseline (1560.217 us; speedup 1.0000x reference)
//
#include <hip/hip_runtime.h>

// PsRoiOffset fused sparse kernel, round 2: LDS-staged weights.
// features (1,200,304,196) f32, rois (512,4) f32,
// W_off (3,3,196,392) f32, b_off (392) f32, out (512,7,7,4) f32.
//
// Block = (bin g, chunk of 8 rois). The 1764x8 weight slice for bin g is
// staged once into LDS (56.4 KB) and reused by 8 rois x 16 corners.
// 256 threads = 16 corners x 16 lanes; each 16-lane group computes the
// 8 conv outputs for one corner (dot of length 1764), then 4 lanes do the
// deformable bilinear fetch, and 16 threads combine the 2x2 samples.

constexpr int H = 200, W = 304, C = 196, CO = 392;
constexpr int KK = 7, DIM = 4, NROI = 512;
constexpr int WROWS = 9 * C;      // 1764
constexpr int RPB = 8;            // rois per block

__global__ __launch_bounds__(256, 2) void psroi_offset_kernel(
    const float* __restrict__ feat, const float* __restrict__ rois,
    const float* __restrict__ Woff, const float* __restrict__ boff,
    float* __restrict__ out)
{
  const int g        = blockIdx.x;          // bin 0..48
  const int roi_base = blockIdx.y * RPB;
  const int bi = g / KK, bj = g % KK;
  const int tid = threadIdx.x;
  const int corner = tid >> 4;              // 0..15 = ycidx*4 + xcidx
  const int lane16 = tid & 15;

  // ---- Stage the bin's weight slice into LDS (half-swizzled rows) ----
  __shared__ float wlds[WROWS * 8];         // 56448 B
  __shared__ float om_lds[16][DIM];
  {
    const float* wsrc = Woff + g * 8;
    for (int row = tid; row < WROWS; row += 256) {
      const float* src = wsrc + (size_t)row * CO;
      const float4 a = *reinterpret_cast<const float4*>(src);
      const float4 b = *reinterpret_cast<const float4*>(src + 4);
      const int base = row * 8;
      const int s = (row & 4) ? 4 : 0;      // swap halves on odd 4-row group
      *reinterpret_cast<float4*>(&wlds[base + s])     = a;
      *reinterpret_cast<float4*>(&wlds[base + 4 - s]) = b;
    }
  }
  __syncthreads();

  for (int r = 0; r < RPB; ++r) {
    const int n = roi_base + r;

    // ---- ROI geometry (redundant per thread) ----
    const float rx1 = rois[n * 4 + 0] * 0.25f;
    const float ry1 = rois[n * 4 + 1] * 0.25f;
    const float rx2 = rois[n * 4 + 2] * 0.25f;
    const float ry2 = rois[n * 4 + 3] * 0.25f;
    const float bh = (ry2 - ry1) * (1.0f / 7.0f);
    const float bw = (rx2 - rx1) * (1.0f / 7.0f);

    int ycand[4], xcand[4];
    float wy[2], wx[2];
#pragma unroll
    for (int si = 0; si < 2; ++si) {
      float sy = ry1 + ((float)bi + ((float)si + 0.5f) * 0.5f) * bh;
      sy = fminf(fmaxf(sy, 0.0f), (float)(H - 1));
      float fy = floorf(sy);
      wy[si] = sy - fy;
      int i0 = (int)fy;
      ycand[2 * si]     = i0;
      ycand[2 * si + 1] = min(i0 + 1, H - 1);

      float sx = rx1 + ((float)bj + ((float)si + 0.5f) * 0.5f) * bw;
      sx = fminf(fmaxf(sx, 0.0f), (float)(W - 1));
      float fx = floorf(sx);
      wx[si] = sx - fx;
      int j0 = (int)fx;
      xcand[2 * si]     = j0;
      xcand[2 * si + 1] = min(j0 + 1, W - 1);
    }

    const int yc = ycand[corner >> 2];
    const int xc = xcand[corner & 3];

    // ---- Conv dot products: weights from LDS, features coalesced ----
    float acc[8];
#pragma unroll
    for (int oo = 0; oo < 8; ++oo) acc[oo] = 0.0f;

#pragma unroll
    for (int p = 0; p < 9; ++p) {
      const int dy = p / 3, dx = p % 3;
      const int ys = yc + dy - 1, xs = xc + dx - 1;
      if (ys < 0 || ys >= H || xs < 0 || xs >= W) continue;  // SAME pad
      const float* frow = feat + ((size_t)(ys * W + xs)) * C;
      const int rbase = p * C;
      for (int ci = lane16; ci < C; ci += 16) {
        const float f = frow[ci];
        const int base = (rbase + ci) * 8;
        const int s = ((rbase + ci) & 4) ? 4 : 0;
        const float4 w0 = *reinterpret_cast<const float4*>(&wlds[base + s]);
        const float4 w1 = *reinterpret_cast<const float4*>(&wlds[base + 4 - s]);
        acc[0] = fmaf(f, w0.x, acc[0]);
        acc[1] = fmaf(f, w0.y, acc[1]);
        acc[2] = fmaf(f, w0.z, acc[2]);
        acc[3] = fmaf(f, w0.w, acc[3]);
        acc[4] = fmaf(f, w1.x, acc[4]);
        acc[5] = fmaf(f, w1.y, acc[5]);
        acc[6] = fmaf(f, w1.z, acc[6]);
        acc[7] = fmaf(f, w1.w, acc[7]);
      }
    }
#pragma unroll
    for (int m = 8; m >= 1; m >>= 1) {
#pragma unroll
      for (int oo = 0; oo < 8; ++oo)
        acc[oo] += __shfl_xor(acc[oo], m, 16);
    }

    // ---- Deformable bilinear fetch (4 lanes per corner) ----
    if (lane16 < DIM) {
      const int d = lane16;
      const int c = g * DIM + d;
      const float offy = acc[2 * d]     + boff[2 * c];
      const float offx = acc[2 * d + 1] + boff[2 * c + 1];
      float yy = fminf(fmaxf((float)yc + offy, 0.0f), (float)(H - 1));
      float xx = fminf(fmaxf((float)xc + offx, 0.0f), (float)(W - 1));
      float fy = floorf(yy), fx = floorf(xx);
      const float ay = yy - fy, ax = xx - fx;
      const int iy0 = (int)fy, ix0 = (int)fx;
      const int iy1 = min(iy0 + 1, H - 1), ix1 = min(ix0 + 1, W - 1);
      const float v00 = feat[((size_t)(iy0 * W + ix0)) * C + c];
      const float v01 = feat[((size_t)(iy0 * W + ix1)) * C + c];
      const float v10 = feat[((size_t)(iy1 * W + ix0)) * C + c];
      const float v11 = feat[((size_t)(iy1 * W + ix1)) * C + c];
      const float top = v00 + (v01 - v00) * ax;
      const float bot = v10 + (v11 - v10) * ax;
      om_lds[corner][d] = top + (bot - top) * ay;
    }
    __syncthreads();

    // ---- Combine 2x2 sample points, mean over samples, store ----
    if (tid < 16) {
      const int si = tid >> 3;
      const int sj = (tid >> 2) & 1;
      const int d  = tid & 3;
      float v = 0.0f;
#pragma unroll
      for (int a = 0; a < 2; ++a) {
#pragma unroll
        for (int b = 0; b < 2; ++b) {
          const float wgt = (a ? wy[si] : 1.0f - wy[si]) *
                            (b ? wx[sj] : 1.0f - wx[sj]);
          v += wgt * om_lds[(2 * si + a) * 4 + (2 * sj + b)][d];
        }
      }
      v += __shfl_xor(v, 4, 16);
      v += __shfl_xor(v, 8, 16);
      if (tid < 4)
        out[(((size_t)n * KK + bi) * KK + bj) * DIM + tid] = 0.25f * v;
    }
    __syncthreads();   // protect om_lds before next roi overwrites it
  }
}

extern "C" void kernel_launch(void* const* d_in, const int* in_sizes, int n_in,
                              void* d_out, int out_size, void* d_ws, size_t ws_size,
                              hipStream_t stream) {
  const float* feat = (const float*)d_in[0];
  const float* rois = (const float*)d_in[1];
  const float* Woff = (const float*)d_in[2];
  const float* boff = (const float*)d_in[3];
  float* out = (float*)d_out;

  psroi_offset_kernel<<<dim3(KK * KK, NROI / RPB), dim3(256), 0, stream>>>(
      feat, rois, Woff, boff, out);
}

// Round 3
// 620.929 us; speedup vs baseline: 2.5127x; 2.5127x over previous
//
#include <hip/hip_runtime.h>

// PsRoiOffset fused sparse kernel, round 3: lane-per-site, scalar weights.
// features (1,200,304,196) f32, rois (512,4) f32,
// W_off (3,3,196,392) f32, b_off (392) f32, out (512,7,7,4) f32.
//
// Block = (bin g, 16 rois). 256 threads = 16 rois x 16 corners; each LANE
// owns one site (roi, corner) and computes the full 1764x8 conv dot for it.
// The weight row needed at each k-step is identical across the whole wave
// (same bin, same k) -> uniform scalar loads, no LDS, no bank conflicts.
// Feature loads are per-lane scattered float4 (L1-cached, 64B line reuse
// across 4 consecutive chunks). OOB taps: divergent if(valid) = zero-pad.

constexpr int H = 200, W = 304, C = 196, CO = 392;
constexpr int KK = 7, DIM = 4, NROI = 512;
constexpr int RPB = 16;   // rois per block (one per 16-lane group)

__global__ __launch_bounds__(256) void psroi_offset_kernel(
    const float* __restrict__ feat, const float* __restrict__ rois,
    const float* __restrict__ Woff, const float* __restrict__ boff,
    float* __restrict__ out)
{
  const int g   = blockIdx.x;                    // bin 0..48 (wave-uniform)
  const int bi  = g / KK, bj = g % KK;
  const int tid = threadIdx.x;
  const int corner = tid & 15;                   // ycidx*4 + xcidx
  const int n   = blockIdx.y * RPB + (tid >> 4); // this lane's roi

  // ---- ROI geometry ----
  const float rx1 = rois[n * 4 + 0] * 0.25f;
  const float ry1 = rois[n * 4 + 1] * 0.25f;
  const float rx2 = rois[n * 4 + 2] * 0.25f;
  const float ry2 = rois[n * 4 + 3] * 0.25f;
  const float bh = (ry2 - ry1) * (1.0f / 7.0f);
  const float bw = (rx2 - rx1) * (1.0f / 7.0f);

  int ycand[4], xcand[4];
  float wy[2], wx[2];
#pragma unroll
  for (int si = 0; si < 2; ++si) {
    float sy = ry1 + ((float)bi + ((float)si + 0.5f) * 0.5f) * bh;
    sy = fminf(fmaxf(sy, 0.0f), (float)(H - 1));
    float fy = floorf(sy);
    wy[si] = sy - fy;
    int i0 = (int)fy;
    ycand[2 * si]     = i0;
    ycand[2 * si + 1] = min(i0 + 1, H - 1);

    float sx = rx1 + ((float)bj + ((float)si + 0.5f) * 0.5f) * bw;
    sx = fminf(fmaxf(sx, 0.0f), (float)(W - 1));
    float fx = floorf(sx);
    wx[si] = sx - fx;
    int j0 = (int)fx;
    xcand[2 * si]     = j0;
    xcand[2 * si + 1] = min(j0 + 1, W - 1);
  }

  const int yc = ycand[corner >> 2];
  const int xc = xcand[corner & 3];

  // ---- Conv dot: 9 taps x 196 ch -> 8 outputs, all in this lane ----
  float acc[8];
#pragma unroll
  for (int o = 0; o < 8; ++o) acc[o] = 0.0f;

#pragma unroll
  for (int p = 0; p < 9; ++p) {
    const int dy = p / 3 - 1, dx = p % 3 - 1;
    const int ys = yc + dy, xs = xc + dx;
    // force the weight base index into an SGPR (wave-uniform)
    const int wbase = __builtin_amdgcn_readfirstlane(p * C * CO + g * 8);
    const bool valid = (ys >= 0) & (ys < H) & (xs >= 0) & (xs < W);
    if (valid) {
      const float* frow = feat + (size_t)(ys * W + xs) * C;
#pragma unroll 7
      for (int cc = 0; cc < C / 4; ++cc) {         // 49 chunks of 4 channels
        const float4 f4 = *reinterpret_cast<const float4*>(frow + cc * 4);
        const float* wr = Woff + wbase + (size_t)(cc * 4) * CO;
        const float fv[4] = {f4.x, f4.y, f4.z, f4.w};
#pragma unroll
        for (int j = 0; j < 4; ++j) {
          const float* wj = wr + (size_t)j * CO;   // uniform pointer
#pragma unroll
          for (int o = 0; o < 8; ++o)
            acc[o] = fmaf(fv[j], wj[o], acc[o]);
        }
      }
    }
  }

  // ---- Bias + deformable bilinear fetch (4 channels, this lane) ----
  const int cbase = g * DIM;
  float om[DIM];
#pragma unroll
  for (int d = 0; d < DIM; ++d) {
    const int c = cbase + d;
    const float offy = acc[2 * d]     + boff[2 * c];
    const float offx = acc[2 * d + 1] + boff[2 * c + 1];
    float yy = fminf(fmaxf((float)yc + offy, 0.0f), (float)(H - 1));
    float xx = fminf(fmaxf((float)xc + offx, 0.0f), (float)(W - 1));
    const float fy = floorf(yy), fx = floorf(xx);
    const float ay = yy - fy, ax = xx - fx;
    const int iy0 = (int)fy, ix0 = (int)fx;
    const int iy1 = min(iy0 + 1, H - 1), ix1 = min(ix0 + 1, W - 1);
    const float v00 = feat[(size_t)(iy0 * W + ix0) * C + c];
    const float v01 = feat[(size_t)(iy0 * W + ix1) * C + c];
    const float v10 = feat[(size_t)(iy1 * W + ix0) * C + c];
    const float v11 = feat[(size_t)(iy1 * W + ix1) * C + c];
    const float top = v00 + (v01 - v00) * ax;
    const float bot = v10 + (v11 - v10) * ax;
    om[d] = top + (bot - top) * ay;
  }

  // ---- Bilinear-combine 16 corners within the 16-lane group ----
  const int yci = corner >> 2, xci = corner & 3;
  const int si = yci >> 1, a = yci & 1;
  const int sj = xci >> 1, b = xci & 1;
  const float cy = a ? wy[si] : 1.0f - wy[si];
  const float cx = b ? wx[sj] : 1.0f - wx[sj];
  const float coef = 0.25f * cy * cx;

  float v[DIM];
#pragma unroll
  for (int d = 0; d < DIM; ++d) v[d] = coef * om[d];
#pragma unroll
  for (int m = 1; m < 16; m <<= 1) {
#pragma unroll
    for (int d = 0; d < DIM; ++d)
      v[d] += __shfl_xor(v[d], m, 16);
  }

  if (corner == 0) {
    float4 o4 = make_float4(v[0], v[1], v[2], v[3]);
    *reinterpret_cast<float4*>(out + (size_t)n * (KK * KK * DIM) + g * DIM) = o4;
  }
}

extern "C" void kernel_launch(void* const* d_in, const int* in_sizes, int n_in,
                              void* d_out, int out_size, void* d_ws, size_t ws_size,
                              hipStream_t stream) {
  const float* feat = (const float*)d_in[0];
  const float* rois = (const float*)d_in[1];
  const float* Woff = (const float*)d_in[2];
  const float* boff = (const float*)d_in[3];
  float* out = (float*)d_out;

  psroi_offset_kernel<<<dim3(KK * KK, NROI / RPB), dim3(256), 0, stream>>>(
      feat, rois, Woff, boff, out);
}

// Round 4
// 415.462 us; speedup vs baseline: 3.7554x; 1.4946x over previous
//
#include <hip/hip_runtime.h>

// PsRoiOffset, round 4: sparse implicit-GEMM with MFMA.
// features (1,200,304,196) f32, rois (512,4) f32,
// W_off (3,3,196,392) f32, b_off (392) f32, out (512,7,7,4) f32.
//
// Block = (bin g, 4 rois) -> 64 sites (4 rois x 16 bilinear corners).
// Per 3x3 tap p: gather the 64 feature rows (196 ch, zero if OOB) into LDS
// as bf16 [64][232], stage the tap's weight slice transposed [16][232]
// (8 real outputs + 8 zero cols), then 4 waves run mfma_f32_16x16x32_bf16
// over K=224 (196 + zero pad). Accumulate across the 9 taps in AGPRs.
// Epilogue: bias, deformable bilinear fetch, 16-corner shuffle combine.

constexpr int H = 200, W = 304, C = 196, CO = 392;
constexpr int KK = 7, DIM = 4, NROI = 512;
constexpr int RPB = 4;                  // rois per block
constexpr int SITES = RPB * 16;         // 64
constexpr int KP = 232;                 // padded per-tap row stride (shorts)

typedef __attribute__((ext_vector_type(8))) short bf16x8;
typedef __attribute__((ext_vector_type(4))) float f32x4;

static __device__ inline unsigned short f2bf(float x) {
  unsigned int u = __float_as_uint(x);
  return (unsigned short)((u + 0x7FFFu + ((u >> 16) & 1u)) >> 16);
}

// candidates/weights for roi n, bin (bi,bj)
static __device__ inline void roi_geom(const float* __restrict__ rois, int n,
                                       int bi, int bj,
                                       int* ycand, int* xcand,
                                       float* wy, float* wx) {
  const float rx1 = rois[n * 4 + 0] * 0.25f;
  const float ry1 = rois[n * 4 + 1] * 0.25f;
  const float rx2 = rois[n * 4 + 2] * 0.25f;
  const float ry2 = rois[n * 4 + 3] * 0.25f;
  const float bh = (ry2 - ry1) * (1.0f / 7.0f);
  const float bw = (rx2 - rx1) * (1.0f / 7.0f);
#pragma unroll
  for (int si = 0; si < 2; ++si) {
    float sy = ry1 + ((float)bi + ((float)si + 0.5f) * 0.5f) * bh;
    sy = fminf(fmaxf(sy, 0.0f), (float)(H - 1));
    float fy = floorf(sy);
    wy[si] = sy - fy;
    int i0 = (int)fy;
    ycand[2 * si] = i0;
    ycand[2 * si + 1] = min(i0 + 1, H - 1);

    float sx = rx1 + ((float)bj + ((float)si + 0.5f) * 0.5f) * bw;
    sx = fminf(fmaxf(sx, 0.0f), (float)(W - 1));
    float fx = floorf(sx);
    wx[si] = sx - fx;
    int j0 = (int)fx;
    xcand[2 * si] = j0;
    xcand[2 * si + 1] = min(j0 + 1, W - 1);
  }
}

__global__ __launch_bounds__(256) void psroi_mfma_kernel(
    const float* __restrict__ feat, const float* __restrict__ rois,
    const float* __restrict__ Woff, const float* __restrict__ boff,
    float* __restrict__ out)
{
  const int g = blockIdx.x;               // bin, wave-uniform
  const int bi = g / KK, bj = g % KK;
  const int roi_base = blockIdx.y * RPB;
  const int tid = threadIdx.x;
  const int lane = tid & 63;
  const int wv = tid >> 6;                // wave id -> M-tile
  const int m_lane = lane & 15;
  const int k_hi = lane >> 4;             // 0..3

  __shared__ short Abuf[SITES * KP];      // [site][k] bf16, 29696 B
  __shared__ short Bbuf[16 * KP];         // [n][k]  bf16, 7424 B
  __shared__ float Cbuf[SITES * 9];       // [site][8+pad], 2304 B

  // ---- zero pad regions (once) ----
  for (int i = tid; i < SITES * (KP - C); i += 256) {
    int row = i / (KP - C), col = C + i % (KP - C);
    Abuf[row * KP + col] = 0;
  }
  for (int i = tid; i < 16 * KP; i += 256) Bbuf[i] = 0;

  // ---- gather-role geometry: this thread loads row gsite = tid>>2 ----
  const int gsite = tid >> 2;
  {
  }
  int gyc, gxc;
  {
    int yc4[4], xc4[4];
    float wy2[2], wx2[2];
    roi_geom(rois, roi_base + (gsite >> 4), bi, bj, yc4, xc4, wy2, wx2);
    const int corner = gsite & 15;
    gyc = yc4[corner >> 2];
    gxc = xc4[corner & 3];
  }

  f32x4 acc = {0.f, 0.f, 0.f, 0.f};

#pragma unroll 1
  for (int p = 0; p < 9; ++p) {
    __syncthreads();   // previous tap's A/B fully consumed (and init done)

    // stage BT[n][k] = W[p][k][g*8+n], bf16
    {
      const float* wsrc = Woff + (size_t)(p * C) * CO + g * 8;
      for (int i = tid; i < C * 8; i += 256) {
        const int ci = i >> 3, o = i & 7;
        Bbuf[o * KP + ci] = (short)f2bf(wsrc[(size_t)ci * CO + o]);
      }
    }
    // gather A rows: 4 lanes per row, consecutive float4 chunks
    {
      const int dy = p / 3 - 1, dx = p % 3 - 1;
      const int ys = gyc + dy, xs = gxc + dx;
      const bool valid = (ys >= 0) && (ys < H) && (xs >= 0) && (xs < W);
      const float* frow = feat + (size_t)(ys * W + xs) * C;
      const int c0 = tid & 3;
      short* arow = &Abuf[gsite * KP];
#pragma unroll
      for (int k = 0; k <= 12; ++k) {
        const int c = c0 + 4 * k;
        if (c < 49) {
          ushort4 w4 = make_ushort4(0, 0, 0, 0);
          if (valid) {
            const float4 f4 = *reinterpret_cast<const float4*>(frow + 4 * c);
            w4.x = f2bf(f4.x); w4.y = f2bf(f4.y);
            w4.z = f2bf(f4.z); w4.w = f2bf(f4.w);
          }
          *reinterpret_cast<ushort4*>(arow + 4 * c) = w4;
        }
      }
    }
    __syncthreads();

    // MFMA: wave wv owns sites 16*wv..16*wv+15; K = 7 steps of 32
    const short* arow = &Abuf[(16 * wv + m_lane) * KP];
    const short* brow = &Bbuf[m_lane * KP];
#pragma unroll
    for (int ks = 0; ks < 7; ++ks) {
      const bf16x8 a = *reinterpret_cast<const bf16x8*>(arow + ks * 32 + k_hi * 8);
      const bf16x8 b = *reinterpret_cast<const bf16x8*>(brow + ks * 32 + k_hi * 8);
      acc = __builtin_amdgcn_mfma_f32_16x16x32_bf16(a, b, acc, 0, 0, 0);
    }
  }

  // ---- C -> LDS: lane holds C[m][n], n = m_lane, m = 16*wv + k_hi*4 + r ----
  if (m_lane < 8) {
#pragma unroll
    for (int r = 0; r < 4; ++r)
      Cbuf[(16 * wv + k_hi * 4 + r) * 9 + m_lane] = acc[r];
  }
  __syncthreads();

  // ---- epilogue: one thread per site (wave 0) ----
  if (tid < 64) {
    const int corner = tid & 15;
    const int rl = tid >> 4;
    const int n = roi_base + rl;

    int yc4[4], xc4[4];
    float wy2[2], wx2[2];
    roi_geom(rois, n, bi, bj, yc4, xc4, wy2, wx2);
    const int yc = yc4[corner >> 2];
    const int xc = xc4[corner & 3];

    const int cbase = g * DIM;
    float om[DIM];
#pragma unroll
    for (int d = 0; d < DIM; ++d) {
      const int c = cbase + d;
      const float offy = Cbuf[tid * 9 + 2 * d]     + boff[2 * c];
      const float offx = Cbuf[tid * 9 + 2 * d + 1] + boff[2 * c + 1];
      float yy = fminf(fmaxf((float)yc + offy, 0.0f), (float)(H - 1));
      float xx = fminf(fmaxf((float)xc + offx, 0.0f), (float)(W - 1));
      const float fy = floorf(yy), fx = floorf(xx);
      const float ay = yy - fy, ax = xx - fx;
      const int iy0 = (int)fy, ix0 = (int)fx;
      const int iy1 = min(iy0 + 1, H - 1), ix1 = min(ix0 + 1, W - 1);
      const float v00 = feat[(size_t)(iy0 * W + ix0) * C + c];
      const float v01 = feat[(size_t)(iy0 * W + ix1) * C + c];
      const float v10 = feat[(size_t)(iy1 * W + ix0) * C + c];
      const float v11 = feat[(size_t)(iy1 * W + ix1) * C + c];
      const float top = v00 + (v01 - v00) * ax;
      const float bot = v10 + (v11 - v10) * ax;
      om[d] = top + (bot - top) * ay;
    }

    // bilinear-combine the 16 corners of this roi within the 16-lane group
    const int yci = corner >> 2, xci = corner & 3;
    const int si = yci >> 1, a = yci & 1;
    const int sj = xci >> 1, b = xci & 1;
    const float cy = a ? wy2[si] : 1.0f - wy2[si];
    const float cx = b ? wx2[sj] : 1.0f - wx2[sj];
    const float coef = 0.25f * cy * cx;

    float v[DIM];
#pragma unroll
    for (int d = 0; d < DIM; ++d) v[d] = coef * om[d];
#pragma unroll
    for (int m = 1; m < 16; m <<= 1) {
#pragma unroll
      for (int d = 0; d < DIM; ++d)
        v[d] += __shfl_xor(v[d], m, 16);
    }

    if (corner == 0) {
      *reinterpret_cast<float4*>(out + (size_t)n * (KK * KK * DIM) + g * DIM) =
          make_float4(v[0], v[1], v[2], v[3]);
    }
  }
}

extern "C" void kernel_launch(void* const* d_in, const int* in_sizes, int n_in,
                              void* d_out, int out_size, void* d_ws, size_t ws_size,
                              hipStream_t stream) {
  const float* feat = (const float*)d_in[0];
  const float* rois = (const float*)d_in[1];
  const float* Woff = (const float*)d_in[2];
  const float* boff = (const float*)d_in[3];
  float* out = (float*)d_out;

  psroi_mfma_kernel<<<dim3(KK * KK, NROI / RPB), dim3(256), 0, stream>>>(
      feat, rois, Woff, boff, out);
}

// Round 5
// 401.150 us; speedup vs baseline: 3.8894x; 1.0357x over previous
//
#include <hip/hip_runtime.h>

// PsRoiOffset, round 5: MFMA + ws-preconverted bf16 weights + XCD swizzle.
// features (1,200,304,196) f32, rois (512,4) f32,
// W_off (3,3,196,392) f32, b_off (392) f32, out (512,7,7,4) f32.
//
// Prep kernel: W_off -> d_ws as bf16 [g(49)][p(9)][n(8)][k(224)], k-padded
// with zeros (196->224). Main kernel: block = (bin g, 4 rois) = 64 sites.
// Per tap: B-fragments load straight from ws into regs (issued before the
// A-gather so HBM/L2 latency hides under it), A rows gathered into LDS as
// bf16 [64][232], then 4 waves x 7 mfma_f32_16x16x32_bf16, acc over taps.

constexpr int H = 200, W = 304, C = 196, CO = 392;
constexpr int KK = 7, DIM = 4, NROI = 512;
constexpr int RPB = 4;                  // rois per block
constexpr int SITES = RPB * 16;         // 64
constexpr int KP = 232;                 // A row stride (shorts)
constexpr int KW = 224;                 // ws per-tap K (padded)
constexpr size_t WS_NEED = (size_t)49 * 9 * 8 * KW * 2;   // 1.58 MB

typedef __attribute__((ext_vector_type(8))) short bf16x8;
typedef __attribute__((ext_vector_type(4))) float f32x4;

static __device__ inline unsigned short f2bf(float x) {
  unsigned int u = __float_as_uint(x);
  return (unsigned short)((u + 0x7FFFu + ((u >> 16) & 1u)) >> 16);
}

static __device__ inline void roi_geom(const float* __restrict__ rois, int n,
                                       int bi, int bj,
                                       int* ycand, int* xcand,
                                       float* wy, float* wx) {
  const float rx1 = rois[n * 4 + 0] * 0.25f;
  const float ry1 = rois[n * 4 + 1] * 0.25f;
  const float rx2 = rois[n * 4 + 2] * 0.25f;
  const float ry2 = rois[n * 4 + 3] * 0.25f;
  const float bh = (ry2 - ry1) * (1.0f / 7.0f);
  const float bw = (rx2 - rx1) * (1.0f / 7.0f);
#pragma unroll
  for (int si = 0; si < 2; ++si) {
    float sy = ry1 + ((float)bi + ((float)si + 0.5f) * 0.5f) * bh;
    sy = fminf(fmaxf(sy, 0.0f), (float)(H - 1));
    float fy = floorf(sy);
    wy[si] = sy - fy;
    int i0 = (int)fy;
    ycand[2 * si] = i0;
    ycand[2 * si + 1] = min(i0 + 1, H - 1);

    float sx = rx1 + ((float)bj + ((float)si + 0.5f) * 0.5f) * bw;
    sx = fminf(fmaxf(sx, 0.0f), (float)(W - 1));
    float fx = floorf(sx);
    wx[si] = sx - fx;
    int j0 = (int)fx;
    xcand[2 * si] = j0;
    xcand[2 * si + 1] = min(j0 + 1, W - 1);
  }
}

// ---- prep: W_off (3,3,196,392) f32 -> ws [49][9][8][224] bf16 ----
__global__ __launch_bounds__(256) void wprep_kernel(
    const float* __restrict__ Woff, unsigned short* __restrict__ wsb)
{
  const int u = blockIdx.x * 256 + threadIdx.x;   // one ushort4 per thread
  const int TOT = 49 * 9 * 8 * (KW / 4);
  if (u >= TOT) return;
  const int k4 = u % (KW / 4);
  const int n  = (u / (KW / 4)) % 8;
  const int p  = (u / (KW / 4 * 8)) % 9;
  const int g  = u / (KW / 4 * 8 * 9);
  const int k  = k4 * 4;
  ushort4 v = make_ushort4(0, 0, 0, 0);
  const int o = g * 8 + n;
#pragma unroll
  for (int j = 0; j < 4; ++j) {
    if (k + j < C) {
      const float w = Woff[(size_t)(p * C + k + j) * CO + o];
      ((unsigned short*)&v)[j] = f2bf(w);
    }
  }
  *reinterpret_cast<ushort4*>(wsb + ((size_t)(g * 9 + p) * 8 + n) * KW + k) = v;
}

template <bool USE_WS>
__global__ __launch_bounds__(256) void psroi_mfma_kernel(
    const float* __restrict__ feat, const float* __restrict__ rois,
    const unsigned short* __restrict__ wsb, const float* __restrict__ Woff,
    const float* __restrict__ boff, float* __restrict__ out)
{
  // XCD-aware swizzle: contiguous work per XCD (6272 % 8 == 0, bijective)
  const int bid = blockIdx.x;
  const int wid = (bid & 7) * (49 * NROI / RPB / 8) + (bid >> 3);
  const int g = wid % 49;                 // bin (wave-uniform)
  const int roi_base = (wid / 49) * RPB;
  const int bi = g / KK, bj = g % KK;
  const int tid = threadIdx.x;
  const int lane = tid & 63;
  const int wv = tid >> 6;
  const int m_lane = lane & 15;
  const int k_hi = lane >> 4;

  __shared__ short Abuf[SITES * KP];                    // 29696 B
  __shared__ short Bbuf[USE_WS ? 8 : 16 * KP];          // fallback only
  __shared__ float Cbuf[SITES * 9];

  // zero A pad cols (persist across taps) and fallback Bbuf
  for (int i = tid; i < SITES * (KP - C); i += 256) {
    int row = i / (KP - C), col = C + i % (KP - C);
    Abuf[row * KP + col] = 0;
  }
  if (!USE_WS) {
    for (int i = tid; i < 16 * KP; i += 256) Bbuf[i] = 0;
  }

  // gather-role geometry: thread loads row gsite = tid>>2 (4 lanes/row)
  const int gsite = tid >> 2;
  int gyc, gxc;
  {
    int yc4[4], xc4[4];
    float wy2[2], wx2[2];
    roi_geom(rois, roi_base + (gsite >> 4), bi, bj, yc4, xc4, wy2, wx2);
    const int corner = gsite & 15;
    gyc = yc4[corner >> 2];
    gxc = xc4[corner & 3];
  }

  f32x4 acc = {0.f, 0.f, 0.f, 0.f};

#pragma unroll 1
  for (int p = 0; p < 9; ++p) {
    __syncthreads();   // previous tap's A consumed (and init done)

    bf16x8 bfr[7];
    if (USE_WS) {
      // B-fragments straight from ws into regs; latency hides under gather
#pragma unroll
      for (int ks = 0; ks < 7; ++ks) bfr[ks] = (bf16x8)(short)0;
      if (m_lane < 8) {
        const unsigned short* wrow =
            wsb + ((size_t)(g * 9 + p) * 8 + m_lane) * KW + k_hi * 8;
#pragma unroll
        for (int ks = 0; ks < 7; ++ks)
          bfr[ks] = *reinterpret_cast<const bf16x8*>(wrow + ks * 32);
      }
    } else {
      const float* wsrc = Woff + (size_t)(p * C) * CO + g * 8;
      for (int i = tid; i < C * 8; i += 256) {
        const int ci = i >> 3, o = i & 7;
        Bbuf[o * KP + ci] = (short)f2bf(wsrc[(size_t)ci * CO + o]);
      }
    }

    // gather A rows: 4 lanes per row, consecutive float4 chunks
    {
      const int dy = p / 3 - 1, dx = p % 3 - 1;
      const int ys = gyc + dy, xs = gxc + dx;
      const bool valid = (ys >= 0) && (ys < H) && (xs >= 0) && (xs < W);
      const float* frow = feat + (size_t)(ys * W + xs) * C;
      const int c0 = tid & 3;
      short* arow = &Abuf[gsite * KP];
#pragma unroll
      for (int k = 0; k <= 12; ++k) {
        const int c = c0 + 4 * k;
        if (c < 49) {
          ushort4 w4 = make_ushort4(0, 0, 0, 0);
          if (valid) {
            const float4 f4 = *reinterpret_cast<const float4*>(frow + 4 * c);
            w4.x = f2bf(f4.x); w4.y = f2bf(f4.y);
            w4.z = f2bf(f4.z); w4.w = f2bf(f4.w);
          }
          *reinterpret_cast<ushort4*>(arow + 4 * c) = w4;
        }
      }
    }
    __syncthreads();

    // MFMA: wave wv owns sites 16*wv..16*wv+15; K = 7 steps of 32
    const short* arow = &Abuf[(16 * wv + m_lane) * KP];
    const short* brow = USE_WS ? nullptr : &Bbuf[m_lane * KP];
#pragma unroll
    for (int ks = 0; ks < 7; ++ks) {
      const bf16x8 a = *reinterpret_cast<const bf16x8*>(arow + ks * 32 + k_hi * 8);
      bf16x8 b;
      if (USE_WS)
        b = bfr[ks];
      else
        b = *reinterpret_cast<const bf16x8*>(brow + ks * 32 + k_hi * 8);
      acc = __builtin_amdgcn_mfma_f32_16x16x32_bf16(a, b, acc, 0, 0, 0);
    }
  }

  // C -> LDS: lane holds C[m][n], n = m_lane, m = 16*wv + k_hi*4 + r
  if (m_lane < 8) {
#pragma unroll
    for (int r = 0; r < 4; ++r)
      Cbuf[(16 * wv + k_hi * 4 + r) * 9 + m_lane] = acc[r];
  }
  __syncthreads();

  // epilogue: one thread per site
  if (tid < 64) {
    const int corner = tid & 15;
    const int n = roi_base + (tid >> 4);

    int yc4[4], xc4[4];
    float wy2[2], wx2[2];
    roi_geom(rois, n, bi, bj, yc4, xc4, wy2, wx2);
    const int yc = yc4[corner >> 2];
    const int xc = xc4[corner & 3];

    const int cbase = g * DIM;
    float om[DIM];
#pragma unroll
    for (int d = 0; d < DIM; ++d) {
      const int c = cbase + d;
      const float offy = Cbuf[tid * 9 + 2 * d]     + boff[2 * c];
      const float offx = Cbuf[tid * 9 + 2 * d + 1] + boff[2 * c + 1];
      float yy = fminf(fmaxf((float)yc + offy, 0.0f), (float)(H - 1));
      float xx = fminf(fmaxf((float)xc + offx, 0.0f), (float)(W - 1));
      const float fy = floorf(yy), fx = floorf(xx);
      const float ay = yy - fy, ax = xx - fx;
      const int iy0 = (int)fy, ix0 = (int)fx;
      const int iy1 = min(iy0 + 1, H - 1), ix1 = min(ix0 + 1, W - 1);
      const float v00 = feat[(size_t)(iy0 * W + ix0) * C + c];
      const float v01 = feat[(size_t)(iy0 * W + ix1) * C + c];
      const float v10 = feat[(size_t)(iy1 * W + ix0) * C + c];
      const float v11 = feat[(size_t)(iy1 * W + ix1) * C + c];
      const float top = v00 + (v01 - v00) * ax;
      const float bot = v10 + (v11 - v10) * ax;
      om[d] = top + (bot - top) * ay;
    }

    const int yci = corner >> 2, xci = corner & 3;
    const int si = yci >> 1, a = yci & 1;
    const int sj = xci >> 1, b = xci & 1;
    const float cy = a ? wy2[si] : 1.0f - wy2[si];
    const float cx = b ? wx2[sj] : 1.0f - wx2[sj];
    const float coef = 0.25f * cy * cx;

    float v[DIM];
#pragma unroll
    for (int d = 0; d < DIM; ++d) v[d] = coef * om[d];
#pragma unroll
    for (int m = 1; m < 16; m <<= 1) {
#pragma unroll
      for (int d = 0; d < DIM; ++d)
        v[d] += __shfl_xor(v[d], m, 16);
    }

    if (corner == 0) {
      *reinterpret_cast<float4*>(out + (size_t)n * (KK * KK * DIM) + g * DIM) =
          make_float4(v[0], v[1], v[2], v[3]);
    }
  }
}

extern "C" void kernel_launch(void* const* d_in, const int* in_sizes, int n_in,
                              void* d_out, int out_size, void* d_ws, size_t ws_size,
                              hipStream_t stream) {
  const float* feat = (const float*)d_in[0];
  const float* rois = (const float*)d_in[1];
  const float* Woff = (const float*)d_in[2];
  const float* boff = (const float*)d_in[3];
  float* out = (float*)d_out;
  unsigned short* wsb = (unsigned short*)d_ws;

  const int nblocks = 49 * NROI / RPB;    // 6272
  if (ws_size >= WS_NEED) {
    const int prep_tot = 49 * 9 * 8 * (KW / 4);
    wprep_kernel<<<dim3((prep_tot + 255) / 256), dim3(256), 0, stream>>>(Woff, wsb);
    psroi_mfma_kernel<true><<<dim3(nblocks), dim3(256), 0, stream>>>(
        feat, rois, wsb, Woff, boff, out);
  } else {
    psroi_mfma_kernel<false><<<dim3(nblocks), dim3(256), 0, stream>>>(
        feat, rois, wsb, Woff, boff, out);
  }
}

// Round 6
// 208.758 us; speedup vs baseline: 7.4738x; 1.9216x over previous
//
#include <hip/hip_runtime.h>

// PsRoiOffset, round 6: per-roi union-patch gather + indirect MFMA.
// features (1,200,304,196) f32, rois (512,4) f32,
// W_off (3,3,196,392) f32, b_off (392) f32, out (512,7,7,4) f32.
//
// Block = one (roi n, bin g). The 16 bilinear corners x 9 conv taps only
// touch an 8x8 union of feature positions (y in {y0-1..y0+2} u {y1-1..y1+2},
// same for x). Stage those 64 rows (196 ch, zero if OOB = SAME pad) into LDS
// as bf16 [64][232] ONCE. Corner/tap -> union row is affine:
// row = (ybase(corner)+dy)*8 + xbase(corner)+dx.
// 4 waves split the 9 taps (p % 4 == wv), each tap = 7 mfma_f32_16x16x32_bf16
// (M=16 corners, N=8 outputs, K=224 padded), B-fragments reg-loaded from the
// ws-preconverted bf16 weights. Partial C summed via LDS. Epilogue: 64
// threads (corner,d): bias, deformable bilinear fetch, shuffle-combine.

constexpr int H = 200, W = 304, C = 196, CO = 392;
constexpr int KK = 7, DIM = 4, NROI = 512;
constexpr int KP = 232;                 // A row stride (shorts)
constexpr int KW = 224;                 // ws per-tap K (padded)
constexpr size_t WS_NEED = (size_t)49 * 9 * 8 * KW * 2;   // 1.58 MB

typedef __attribute__((ext_vector_type(8))) short bf16x8;
typedef __attribute__((ext_vector_type(4))) float f32x4;

static __device__ inline unsigned short f2bf(float x) {
  unsigned int u = __float_as_uint(x);
  return (unsigned short)((u + 0x7FFFu + ((u >> 16) & 1u)) >> 16);
}

static __device__ inline void roi_geom(const float* __restrict__ rois, int n,
                                       int bi, int bj,
                                       int* ycand, int* xcand,
                                       float* wy, float* wx) {
  const float rx1 = rois[n * 4 + 0] * 0.25f;
  const float ry1 = rois[n * 4 + 1] * 0.25f;
  const float rx2 = rois[n * 4 + 2] * 0.25f;
  const float ry2 = rois[n * 4 + 3] * 0.25f;
  const float bh = (ry2 - ry1) * (1.0f / 7.0f);
  const float bw = (rx2 - rx1) * (1.0f / 7.0f);
#pragma unroll
  for (int si = 0; si < 2; ++si) {
    float sy = ry1 + ((float)bi + ((float)si + 0.5f) * 0.5f) * bh;
    sy = fminf(fmaxf(sy, 0.0f), (float)(H - 1));
    float fy = floorf(sy);
    wy[si] = sy - fy;
    int i0 = (int)fy;
    ycand[2 * si] = i0;
    ycand[2 * si + 1] = min(i0 + 1, H - 1);

    float sx = rx1 + ((float)bj + ((float)si + 0.5f) * 0.5f) * bw;
    sx = fminf(fmaxf(sx, 0.0f), (float)(W - 1));
    float fx = floorf(sx);
    wx[si] = sx - fx;
    int j0 = (int)fx;
    xcand[2 * si] = j0;
    xcand[2 * si + 1] = min(j0 + 1, W - 1);
  }
}

// ---- prep: W_off (3,3,196,392) f32 -> ws [49][9][8][224] bf16 ----
__global__ __launch_bounds__(256) void wprep_kernel(
    const float* __restrict__ Woff, unsigned short* __restrict__ wsb)
{
  const int u = blockIdx.x * 256 + threadIdx.x;
  const int TOT = 49 * 9 * 8 * (KW / 4);
  if (u >= TOT) return;
  const int k4 = u % (KW / 4);
  const int n  = (u / (KW / 4)) % 8;
  const int p  = (u / (KW / 4 * 8)) % 9;
  const int g  = u / (KW / 4 * 8 * 9);
  const int k  = k4 * 4;
  ushort4 v = make_ushort4(0, 0, 0, 0);
  const int o = g * 8 + n;
#pragma unroll
  for (int j = 0; j < 4; ++j) {
    if (k + j < C) {
      const float w = Woff[(size_t)(p * C + k + j) * CO + o];
      ((unsigned short*)&v)[j] = f2bf(w);
    }
  }
  *reinterpret_cast<ushort4*>(wsb + ((size_t)(g * 9 + p) * 8 + n) * KW + k) = v;
}

template <bool USE_WS>
__global__ __launch_bounds__(256) void psroi_union_kernel(
    const float* __restrict__ feat, const float* __restrict__ rois,
    const unsigned short* __restrict__ wsb, const float* __restrict__ Woff,
    const float* __restrict__ boff, float* __restrict__ out)
{
  // XCD-aware swizzle (25088 % 8 == 0, bijective); consecutive wid = same roi
  const int bid = blockIdx.x;
  const int wid = (bid & 7) * (49 * NROI / 8) + (bid >> 3);
  const int g = wid % 49;               // bin (wave-uniform)
  const int n = wid / 49;               // roi
  const int bi = g / KK, bj = g % KK;
  const int tid = threadIdx.x;
  const int lane = tid & 63;
  const int wv = tid >> 6;
  const int m_lane = lane & 15;
  const int k_hi = lane >> 4;

  __shared__ short Abuf[64 * KP];       // union rows, 29696 B
  __shared__ float Cbuf[4 * 16 * 9];    // per-wave partial C, 2304 B

  // zero the K-pad columns (196..231) once
  for (int i = tid; i < 64 * (KP - C); i += 256) {
    const int row = i / (KP - C), col = C + i % (KP - C);
    Abuf[row * KP + col] = 0;
  }

  int yc4[4], xc4[4];
  float wy2[2], wx2[2];
  roi_geom(rois, n, bi, bj, yc4, xc4, wy2, wx2);

  // ---- Stage the 8x8 union patch: 4 lanes per position ----
  {
    const int pos = tid >> 2;           // 0..63 = yi*8 + xi
    const int yi = pos >> 3, xi = pos & 7;
    const int yrow = (yi < 4) ? (yc4[0] + yi - 1) : (yc4[2] + yi - 5);
    const int xcol = (xi < 4) ? (xc4[0] + xi - 1) : (xc4[2] + xi - 5);
    const bool valid = (yrow >= 0) && (yrow < H) && (xcol >= 0) && (xcol < W);
    const float* frow = feat + (size_t)(yrow * W + xcol) * C;
    short* arow = &Abuf[pos * KP];
    const int l = tid & 3;
#pragma unroll
    for (int k = 0; k <= 12; ++k) {
      const int c = l + 4 * k;          // float4 chunk index, 49 chunks
      if (c < 49) {
        ushort4 v = make_ushort4(0, 0, 0, 0);
        if (valid) {
          const float4 f4 = *reinterpret_cast<const float4*>(frow + 4 * c);
          v.x = f2bf(f4.x); v.y = f2bf(f4.y);
          v.z = f2bf(f4.z); v.w = f2bf(f4.w);
        }
        *reinterpret_cast<ushort4*>(arow + 4 * c) = v;
      }
    }
  }
  __syncthreads();

  // ---- MFMA: wave wv takes taps p with p%4==wv; corner = m_lane ----
  const int i0 = m_lane >> 2, j0 = m_lane & 3;
  const int dyA = yc4[1] - yc4[0], dyB = yc4[3] - yc4[2];
  const int dxA = xc4[1] - xc4[0], dxB = xc4[3] - xc4[2];
  int ybase = (i0 & 2) ? 5 : 1;
  ybase += (i0 & 1) ? ((i0 & 2) ? dyB : dyA) : 0;
  int xbase = (j0 & 2) ? 5 : 1;
  xbase += (j0 & 1) ? ((j0 & 2) ? dxB : dxA) : 0;

  f32x4 acc = {0.f, 0.f, 0.f, 0.f};

#pragma unroll 1
  for (int p = wv; p < 9; p += 4) {
    bf16x8 bfr[7];
#pragma unroll
    for (int ks = 0; ks < 7; ++ks) bfr[ks] = (bf16x8)(short)0;
    if (m_lane < 8) {
      if (USE_WS) {
        const unsigned short* wrow =
            wsb + ((size_t)(g * 9 + p) * 8 + m_lane) * KW + k_hi * 8;
#pragma unroll
        for (int ks = 0; ks < 7; ++ks)
          bfr[ks] = *reinterpret_cast<const bf16x8*>(wrow + ks * 32);
      } else {
#pragma unroll
        for (int ks = 0; ks < 7; ++ks) {
          bf16x8 b = (bf16x8)(short)0;
#pragma unroll
          for (int j = 0; j < 8; ++j) {
            const int k = ks * 32 + k_hi * 8 + j;
            if (k < C)
              b[j] = (short)f2bf(Woff[(size_t)(p * C + k) * CO + g * 8 + m_lane]);
          }
          bfr[ks] = b;
        }
      }
    }

    const int row = (ybase + p / 3 - 1) * 8 + (xbase + p % 3 - 1);
    const short* arow = &Abuf[row * KP];
#pragma unroll
    for (int ks = 0; ks < 7; ++ks) {
      const bf16x8 a = *reinterpret_cast<const bf16x8*>(arow + ks * 32 + k_hi * 8);
      acc = __builtin_amdgcn_mfma_f32_16x16x32_bf16(a, bfr[ks], acc, 0, 0, 0);
    }
  }

  // partial C -> LDS: lane holds C[site][n], site = k_hi*4+r, n = m_lane
  if (m_lane < 8) {
#pragma unroll
    for (int r = 0; r < 4; ++r)
      Cbuf[(wv * 16 + k_hi * 4 + r) * 9 + m_lane] = acc[r];
  }
  __syncthreads();

  // ---- Epilogue: 64 threads = (corner, d) ----
  if (tid < 64) {
    const int corner = tid >> 2;
    const int d = tid & 3;
    const int yc = yc4[corner >> 2];
    const int xc = xc4[corner & 3];
    const int c = g * DIM + d;

    float offy = boff[2 * c], offx = boff[2 * c + 1];
#pragma unroll
    for (int w = 0; w < 4; ++w) {
      offy += Cbuf[(w * 16 + corner) * 9 + 2 * d];
      offx += Cbuf[(w * 16 + corner) * 9 + 2 * d + 1];
    }

    float yy = fminf(fmaxf((float)yc + offy, 0.0f), (float)(H - 1));
    float xx = fminf(fmaxf((float)xc + offx, 0.0f), (float)(W - 1));
    const float fy = floorf(yy), fx = floorf(xx);
    const float ay = yy - fy, ax = xx - fx;
    const int iy0 = (int)fy, ix0 = (int)fx;
    const int iy1 = min(iy0 + 1, H - 1), ix1 = min(ix0 + 1, W - 1);
    const float v00 = feat[(size_t)(iy0 * W + ix0) * C + c];
    const float v01 = feat[(size_t)(iy0 * W + ix1) * C + c];
    const float v10 = feat[(size_t)(iy1 * W + ix0) * C + c];
    const float v11 = feat[(size_t)(iy1 * W + ix1) * C + c];
    const float top = v00 + (v01 - v00) * ax;
    const float bot = v10 + (v11 - v10) * ax;
    const float om = top + (bot - top) * ay;

    const int yci = corner >> 2, xci = corner & 3;
    const int si = yci >> 1, a = yci & 1;
    const int sj = xci >> 1, b = xci & 1;
    const float cy = a ? wy2[si] : 1.0f - wy2[si];
    const float cx = b ? wx2[sj] : 1.0f - wx2[sj];
    float v = 0.25f * cy * cx * om;

    // sum over the 16 corners (lane = corner*4 + d)
    v += __shfl_xor(v, 4);
    v += __shfl_xor(v, 8);
    v += __shfl_xor(v, 16);
    v += __shfl_xor(v, 32);

    if (tid < 4)
      out[(size_t)n * (KK * KK * DIM) + g * DIM + tid] = v;
  }
}

extern "C" void kernel_launch(void* const* d_in, const int* in_sizes, int n_in,
                              void* d_out, int out_size, void* d_ws, size_t ws_size,
                              hipStream_t stream) {
  const float* feat = (const float*)d_in[0];
  const float* rois = (const float*)d_in[1];
  const float* Woff = (const float*)d_in[2];
  const float* boff = (const float*)d_in[3];
  float* out = (float*)d_out;
  unsigned short* wsb = (unsigned short*)d_ws;

  const int nblocks = 49 * NROI;          // 25088
  if (ws_size >= WS_NEED) {
    const int prep_tot = 49 * 9 * 8 * (KW / 4);
    wprep_kernel<<<dim3((prep_tot + 255) / 256), dim3(256), 0, stream>>>(Woff, wsb);
    psroi_union_kernel<true><<<dim3(nblocks), dim3(256), 0, stream>>>(
        feat, rois, wsb, Woff, boff, out);
  } else {
    psroi_union_kernel<false><<<dim3(nblocks), dim3(256), 0, stream>>>(
        feat, rois, wsb, Woff, boff, out);
  }
}